// Round 4
// baseline (523.688 us; speedup 1.0000x reference)
//
#include <hip/hip_runtime.h>

// ---------------------------------------------------------------------------
// Controller: 4-layer LSTM stack + two heads.
// z = [x, h_prev[l], prev_layer]; K=1536 slice (x,h_prev) for ALL layers is
// one parallel GEMM (gemm_gates); K=1024 prev-layer slice is sequential
// (gemm_seq -> cell_seq). Layer 0 prev-contribution == 0 -> cell0.
//
// R4: m97-style GEMM structure everywhere: single-buffered LDS (<=24KB),
// 2 barriers per k-tile, no register dbuf (lean VGPR), small tiles for
// high block counts (4+ blocks/CU, 16 waves/CU), XCD swizzle kept.
//
// ws layout (bytes):
//   A0      @ 0        : bf16 [4][512][1536]   6,291,456
//   G       @ 6291456  : f32  [4][512][4096]  33,554,432  (bias folded)
//   hidden  @ 39845888 : bf16 [512][4096]      4,194,304
//   scratch @ 44040192 : f32  16,777,216 B  (seq partials [2][512][4096],
//                        later heads partials [8][512][768])
// ---------------------------------------------------------------------------

typedef short    shortx8  __attribute__((ext_vector_type(8)));
typedef float    floatx16 __attribute__((ext_vector_type(16)));

__device__ __forceinline__ unsigned int f2bf1(float x) {
  unsigned int u = __float_as_uint(x);
  return (u + 0x7fffu + ((u >> 16) & 1u)) >> 16;   // RNE to bf16 bits
}
__device__ __forceinline__ unsigned int f2bf2(float lo, float hi) {
  return f2bf1(lo) | (f2bf1(hi) << 16);
}
__device__ __forceinline__ float sigm(float x) { return 1.f / (1.f + __expf(-x)); }
__device__ __forceinline__ float tanh_(float x) { return 1.f - 2.f / (__expf(2.f * x) + 1.f); }

// ---------------------------------------------------------------------------
// prep_a0: A0[l][b][0:1536] = bf16(x[b] ++ h_prev[l][b]).  grid (384,4) x 256
// ---------------------------------------------------------------------------
__global__ __launch_bounds__(256) void prep_a0(const float* __restrict__ x,
                                               const float* __restrict__ hp,
                                               unsigned short* __restrict__ A0) {
  const int l   = blockIdx.y;
  const int idx = blockIdx.x * 256 + threadIdx.x;   // < 512*192
  const int b   = idx / 192;
  const int kk  = (idx - b * 192) * 8;
  float v[8];
  if (kk < 512) {
    const float* s = x + (size_t)b * 512 + kk;
#pragma unroll
    for (int i = 0; i < 8; ++i) v[i] = s[i];
  } else {
    const float* s = hp + ((size_t)l * 512 + b) * 1024 + (kk - 512);
#pragma unroll
    for (int i = 0; i < 8; ++i) v[i] = s[i];
  }
  uint4 o;
  o.x = f2bf2(v[0], v[1]); o.y = f2bf2(v[2], v[3]);
  o.z = f2bf2(v[4], v[5]); o.w = f2bf2(v[6], v[7]);
  *(uint4*)(A0 + ((size_t)l * 512 + b) * 1536 + kk) = o;
}

// ---------------------------------------------------------------------------
// gemm_gates: G[l][b][n] = bg[l][n] + sum_{k<1536} A0[l][b][k]*Wg[l][n][k]
// BM=128 BN=64 BK=64, 256 thr = 4 waves (2m x 2n of 64x32), single-buffer
// LDS 24KB, 2 barriers/ktile. grid 1024 linear, XCD-swizzled (4 m-tiles of
// one (l,nt) share an XCD).
// ---------------------------------------------------------------------------
__global__ __launch_bounds__(256, 4) void gemm_gates(
    const unsigned short* __restrict__ A0, const float* __restrict__ Wg,
    const float* __restrict__ bg, float* __restrict__ G) {
  __shared__ __align__(16) unsigned short As[128 * 64];  // 16 KB
  __shared__ __align__(16) unsigned short Bs[64 * 64];   //  8 KB
  const int tid = threadIdx.x, lane = tid & 63, wave = tid >> 6;
  const int id  = blockIdx.x;
  const int xcd = id & 7, j = id >> 3;     // j 0..127
  const int mt  = j & 3, rest = j >> 2;    // rest 0..31
  const int c   = xcd * 32 + rest;         // 0..255
  const int l   = c >> 6, nt = c & 63;
  const int mbase = mt * 128, nbase = nt * 64;
  const unsigned short* Ab = A0 + ((size_t)l * 512 + mbase) * 1536;
  const float*          Bb = Wg + (size_t)l * 4096 * 2560 + (size_t)nbase * 2560;
  const int arow = tid >> 3;     // 0..31 (+32 per round)
  const int akg  = tid & 7;

  floatx16 acc[2];
#pragma unroll
  for (int r = 0; r < 16; ++r) { acc[0][r] = 0.f; acc[1][r] = 0.f; }
  const int wm = (wave >> 1) * 64, wn = (wave & 1) * 32;

  for (int kt = 0; kt < 24; ++kt) {
    const int kg = kt * 64;
    uint4 av[4];
#pragma unroll
    for (int r = 0; r < 4; ++r)
      av[r] = *(const uint4*)(Ab + (size_t)(arow + r * 32) * 1536 + kg + akg * 8);
    float4 bv[4];
#pragma unroll
    for (int u = 0; u < 4; ++u) {
      const int idx = u * 256 + tid;
      bv[u] = *(const float4*)(Bb + (size_t)(idx >> 4) * 2560 + kg + (idx & 15) * 4);
    }
    __syncthreads();   // all waves done reading LDS of previous tile
#pragma unroll
    for (int r = 0; r < 4; ++r) {
      const int row = arow + r * 32;
      *(uint4*)(&As[row * 64 + ((akg ^ (row & 7)) * 8)]) = av[r];
    }
#pragma unroll
    for (int u = 0; u < 4; ++u) {
      const int idx = u * 256 + tid;
      const int n = idx >> 4, kc = (idx & 15) * 4;
      uint2 pk;
      pk.x = f2bf2(bv[u].x, bv[u].y);
      pk.y = f2bf2(bv[u].z, bv[u].w);
      *(uint2*)(&Bs[n * 64 + (((kc >> 3) ^ (n & 7)) * 8) + (kc & 4)]) = pk;
    }
    __syncthreads();
#pragma unroll
    for (int ks = 0; ks < 4; ++ks) {
      const int gb = ks * 2 + (lane >> 5);
      const int rowb = wn + (lane & 31);
      const shortx8 bfv = *(const shortx8*)(&Bs[rowb * 64 + ((gb ^ (rowb & 7)) * 8)]);
#pragma unroll
      for (int sm = 0; sm < 2; ++sm) {
        const int rowa = wm + sm * 32 + (lane & 31);
        const shortx8 af = *(const shortx8*)(&As[rowa * 64 + ((gb ^ (rowa & 7)) * 8)]);
        acc[sm] = __builtin_amdgcn_mfma_f32_32x32x16_bf16(af, bfv, acc[sm], 0, 0, 0);
      }
    }
  }

  const int col = nbase + wn + (lane & 31);
  const float bias = bg[(size_t)l * 4096 + col];
  float* Gl = G + ((size_t)l * 512 + mbase) * 4096;
#pragma unroll
  for (int sm = 0; sm < 2; ++sm)
#pragma unroll
    for (int r = 0; r < 16; ++r) {
      const int row = wm + sm * 32 + ((r & 3) + 8 * (r >> 2) + 4 * (lane >> 5));
      Gl[(size_t)row * 4096 + col] = acc[sm][r] + bias;
    }
}

// ---------------------------------------------------------------------------
// cell0: layer 0 pure pointwise on G[0].  grid 512 x 256.
// ---------------------------------------------------------------------------
__global__ __launch_bounds__(256) void cell0(const float* __restrict__ G,
                                             const float* __restrict__ cp_l,
                                             unsigned short* __restrict__ hidden) {
  const int idx = (blockIdx.x * 256 + threadIdx.x) * 4;
  const int b = idx >> 10, h = idx & 1023;
  const float* g0 = G + (size_t)b * 4096;
  const float4 vi = *(const float4*)(g0 + h);
  const float4 vf = *(const float4*)(g0 + 1024 + h);
  const float4 vo = *(const float4*)(g0 + 2048 + h);
  const float4 vs = *(const float4*)(g0 + 3072 + h);
  const float4 cp = *(const float4*)(cp_l + (size_t)b * 1024 + h);
  const float gi[4] = {vi.x, vi.y, vi.z, vi.w};
  const float gf[4] = {vf.x, vf.y, vf.z, vf.w};
  const float go[4] = {vo.x, vo.y, vo.z, vo.w};
  const float gs[4] = {vs.x, vs.y, vs.z, vs.w};
  const float cc[4] = {cp.x, cp.y, cp.z, cp.w};
  float hn[4];
#pragma unroll
  for (int jj = 0; jj < 4; ++jj) {
    const float c = sigm(gf[jj]) * cc[jj] + sigm(gi[jj]) * tanh_(gs[jj]);
    hn[jj] = sigm(go[jj]) * tanh_(c);
  }
  uint2 o;
  o.x = f2bf2(hn[0], hn[1]);
  o.y = f2bf2(hn[2], hn[3]);
  *(uint2*)(hidden + (size_t)b * 4096 + h) = o;
}

// ---------------------------------------------------------------------------
// gemm_seq: p[ks][b][n] = sum_{k in split} h_{l-1}[b][k]*Wg[l][n][1536+k]
// BM=BN=64 BK=64, 4 waves of 32x32, single-buffer LDS 16KB, split-K=2.
// grid 1024 linear, XCD-swizzled (8 m-tiles of one (nt,ks) share an XCD).
// ---------------------------------------------------------------------------
__global__ __launch_bounds__(256, 4) void gemm_seq(
    const unsigned short* __restrict__ hidden_ro, const float* __restrict__ Wg,
    float* __restrict__ P, int l) {
  __shared__ __align__(16) unsigned short As[64 * 64];   // 8 KB
  __shared__ __align__(16) unsigned short Bs[64 * 64];   // 8 KB
  const int tid = threadIdx.x, lane = tid & 63, wave = tid >> 6;
  const int id  = blockIdx.x;
  const int xcd = id & 7, j = id >> 3;     // j 0..127
  const int mt  = j & 7, rest = j >> 3;    // rest 0..15
  const int c   = xcd * 16 + rest;         // 0..127
  const int nt  = c & 63, ks0 = c >> 6;    // ks0 0..1
  const int mbase = mt * 64, nbase = nt * 64;
  const int k0 = ks0 * 512;
  const unsigned short* Ab = hidden_ro + (size_t)(l - 1) * 1024;      // lda 4096
  const float* Bb = Wg + (size_t)l * 4096 * 2560 + 1536 + (size_t)nbase * 2560;
  const int arow = tid >> 3;     // 0..31 (+32 per round)
  const int akg  = tid & 7;

  floatx16 acc;
#pragma unroll
  for (int r = 0; r < 16; ++r) acc[r] = 0.f;
  const int wm = (wave & 1) * 32, wn = (wave >> 1) * 32;

  for (int kt = 0; kt < 8; ++kt) {
    const int kg = k0 + kt * 64;
    uint4 av[2];
#pragma unroll
    for (int r = 0; r < 2; ++r)
      av[r] = *(const uint4*)(Ab + (size_t)(mbase + arow + r * 32) * 4096 + kg + akg * 8);
    float4 bv[4];
#pragma unroll
    for (int u = 0; u < 4; ++u) {
      const int idx = u * 256 + tid;
      bv[u] = *(const float4*)(Bb + (size_t)(idx >> 4) * 2560 + kg + (idx & 15) * 4);
    }
    __syncthreads();
#pragma unroll
    for (int r = 0; r < 2; ++r) {
      const int row = arow + r * 32;
      *(uint4*)(&As[row * 64 + ((akg ^ (row & 7)) * 8)]) = av[r];
    }
#pragma unroll
    for (int u = 0; u < 4; ++u) {
      const int idx = u * 256 + tid;
      const int n = idx >> 4, kc = (idx & 15) * 4;
      uint2 pk;
      pk.x = f2bf2(bv[u].x, bv[u].y);
      pk.y = f2bf2(bv[u].z, bv[u].w);
      *(uint2*)(&Bs[n * 64 + (((kc >> 3) ^ (n & 7)) * 8) + (kc & 4)]) = pk;
    }
    __syncthreads();
#pragma unroll
    for (int ks = 0; ks < 4; ++ks) {
      const int gb = ks * 2 + (lane >> 5);
      const int rowa = wm + (lane & 31);
      const int rowb = wn + (lane & 31);
      const shortx8 af  = *(const shortx8*)(&As[rowa * 64 + ((gb ^ (rowa & 7)) * 8)]);
      const shortx8 bfv = *(const shortx8*)(&Bs[rowb * 64 + ((gb ^ (rowb & 7)) * 8)]);
      acc = __builtin_amdgcn_mfma_f32_32x32x16_bf16(af, bfv, acc, 0, 0, 0);
    }
  }

  float* Co = P + (size_t)ks0 * 512 * 4096;
  const int col = nbase + wn + (lane & 31);
#pragma unroll
  for (int r = 0; r < 16; ++r) {
    const int row = mbase + wm + ((r & 3) + 8 * (r >> 2) + 4 * (lane >> 5));
    Co[(size_t)row * 4096 + col] = acc[r];
  }
}

// ---------------------------------------------------------------------------
// cell_seq: g = p0+p1+G[l] ; LSTM cell -> hidden slice l.  grid 512 x 256.
// ---------------------------------------------------------------------------
__global__ __launch_bounds__(256) void cell_seq(
    const float* __restrict__ P, const float* __restrict__ G_l,
    const float* __restrict__ cp_l, unsigned short* __restrict__ hidden, int l) {
  const int idx = (blockIdx.x * 256 + threadIdx.x) * 4;
  const int b = idx >> 10, h = idx & 1023;
  const float* p0 = P + (size_t)b * 4096;
  const float* p1 = P + (size_t)512 * 4096 + (size_t)b * 4096;
  const float* g0 = G_l + (size_t)b * 4096;
  float gv[4][4];
#pragma unroll
  for (int g = 0; g < 4; ++g) {
    const float4 a = *(const float4*)(p0 + g * 1024 + h);
    const float4 bb = *(const float4*)(p1 + g * 1024 + h);
    const float4 cg = *(const float4*)(g0 + g * 1024 + h);
    gv[g][0] = a.x + bb.x + cg.x;
    gv[g][1] = a.y + bb.y + cg.y;
    gv[g][2] = a.z + bb.z + cg.z;
    gv[g][3] = a.w + bb.w + cg.w;
  }
  const float4 cp = *(const float4*)(cp_l + (size_t)b * 1024 + h);
  const float cc[4] = {cp.x, cp.y, cp.z, cp.w};
  float hn[4];
#pragma unroll
  for (int jj = 0; jj < 4; ++jj) {
    const float c = sigm(gv[1][jj]) * cc[jj] + sigm(gv[0][jj]) * tanh_(gv[3][jj]);
    hn[jj] = sigm(gv[2][jj]) * tanh_(c);
  }
  uint2 o;
  o.x = f2bf2(hn[0], hn[1]);
  o.y = f2bf2(hn[2], hn[3]);
  *(uint2*)(hidden + (size_t)b * 4096 + l * 1024 + h) = o;
}

// ---------------------------------------------------------------------------
// gemm_heads: p[ks][b][n] = sum hidden[b][k]*W[n][k], W = [W_y; W_E].
// BM=BN=64, split-K=8 (512 each), grid 768 linear XCD-swizzled.
// ---------------------------------------------------------------------------
__global__ __launch_bounds__(256, 4) void gemm_heads(
    const unsigned short* __restrict__ A, const float* __restrict__ Wy,
    const float* __restrict__ WE, float* __restrict__ P) {
  __shared__ __align__(16) unsigned short As[64 * 64];
  __shared__ __align__(16) unsigned short Bs[64 * 64];
  const int tid = threadIdx.x, lane = tid & 63, wave = tid >> 6;
  const int id  = blockIdx.x;
  const int xcd = id & 7, j = id >> 3;     // j 0..95
  const int mt  = j & 7, rest = j >> 3;    // rest 0..11
  const int c   = xcd * 12 + rest;         // 0..95
  const int nt  = c % 12, ks0 = c / 12;    // ks0 0..7
  const int mbase = mt * 64, nbase = nt * 64;
  const int k0 = ks0 * 512;
  const float* Bb = (nt < 8) ? (Wy + (size_t)nbase * 4096)
                             : (WE + (size_t)(nbase - 512) * 4096);
  const unsigned short* Ab = A;
  const int arow = tid >> 3;
  const int akg  = tid & 7;

  floatx16 acc;
#pragma unroll
  for (int r = 0; r < 16; ++r) acc[r] = 0.f;
  const int wm = (wave & 1) * 32, wn = (wave >> 1) * 32;

  for (int kt = 0; kt < 8; ++kt) {
    const int kg = k0 + kt * 64;
    uint4 av[2];
#pragma unroll
    for (int r = 0; r < 2; ++r)
      av[r] = *(const uint4*)(Ab + (size_t)(mbase + arow + r * 32) * 4096 + kg + akg * 8);
    float4 bv[4];
#pragma unroll
    for (int u = 0; u < 4; ++u) {
      const int idx = u * 256 + tid;
      bv[u] = *(const float4*)(Bb + (size_t)(idx >> 4) * 4096 + kg + (idx & 15) * 4);
    }
    __syncthreads();
#pragma unroll
    for (int r = 0; r < 2; ++r) {
      const int row = arow + r * 32;
      *(uint4*)(&As[row * 64 + ((akg ^ (row & 7)) * 8)]) = av[r];
    }
#pragma unroll
    for (int u = 0; u < 4; ++u) {
      const int idx = u * 256 + tid;
      const int n = idx >> 4, kc = (idx & 15) * 4;
      uint2 pk;
      pk.x = f2bf2(bv[u].x, bv[u].y);
      pk.y = f2bf2(bv[u].z, bv[u].w);
      *(uint2*)(&Bs[n * 64 + (((kc >> 3) ^ (n & 7)) * 8) + (kc & 4)]) = pk;
    }
    __syncthreads();
#pragma unroll
    for (int ks = 0; ks < 4; ++ks) {
      const int gb = ks * 2 + (lane >> 5);
      const int rowa = wm + (lane & 31);
      const int rowb = wn + (lane & 31);
      const shortx8 af  = *(const shortx8*)(&As[rowa * 64 + ((gb ^ (rowa & 7)) * 8)]);
      const shortx8 bfv = *(const shortx8*)(&Bs[rowb * 64 + ((gb ^ (rowb & 7)) * 8)]);
      acc = __builtin_amdgcn_mfma_f32_32x32x16_bf16(af, bfv, acc, 0, 0, 0);
    }
  }

  float* Co = P + (size_t)ks0 * 512 * 768;
  const int col = nbase + wn + (lane & 31);
#pragma unroll
  for (int r = 0; r < 16; ++r) {
    const int row = mbase + wm + ((r & 3) + 8 * (r >> 2) + 4 * (lane >> 5));
    Co[(size_t)row * 768 + col] = acc[r];
  }
}

// ---------------------------------------------------------------------------
// head_reduce: sum 8 k-split partials + bias -> d_out.  grid (3,512) x 256
// ---------------------------------------------------------------------------
__global__ __launch_bounds__(256) void head_reduce(
    const float* __restrict__ hp, const float* __restrict__ b_y,
    const float* __restrict__ b_E, float* __restrict__ out) {
  const int n = blockIdx.x * 256 + threadIdx.x;  // 0..767
  const int b = blockIdx.y;
  float s = 0.f;
#pragma unroll
  for (int ks = 0; ks < 8; ++ks)
    s += hp[(size_t)ks * 512 * 768 + (size_t)b * 768 + n];
  if (n < 512)
    out[(size_t)b * 512 + n] = s + b_y[n];
  else
    out[(size_t)512 * 512 + (size_t)b * 256 + (n - 512)] = s + b_E[n - 512];
}

// ---------------------------------------------------------------------------
extern "C" void kernel_launch(void* const* d_in, const int* in_sizes, int n_in,
                              void* d_out, int out_size, void* d_ws, size_t ws_size,
                              hipStream_t stream) {
  const float* x      = (const float*)d_in[0];
  const float* h_prev = (const float*)d_in[1];
  const float* c_prev = (const float*)d_in[2];
  const float* Wg     = (const float*)d_in[3];
  const float* bg     = (const float*)d_in[4];
  const float* W_y    = (const float*)d_in[5];
  const float* b_y    = (const float*)d_in[6];
  const float* W_E    = (const float*)d_in[7];
  const float* b_E    = (const float*)d_in[8];

  char* ws = (char*)d_ws;
  unsigned short* A0      = (unsigned short*)(ws + 0);
  float*          G       = (float*)(ws + 6291456);
  unsigned short* hidden  = (unsigned short*)(ws + 39845888);
  float*          scratch = (float*)(ws + 44040192);

  prep_a0<<<dim3(384, 4), 256, 0, stream>>>(x, h_prev, A0);
  gemm_gates<<<1024, 256, 0, stream>>>(A0, Wg, bg, G);
  cell0<<<512, 256, 0, stream>>>(G, c_prev, hidden);
  for (int l = 1; l < 4; ++l) {
    gemm_seq<<<1024, 256, 0, stream>>>(hidden, Wg, scratch, l);
    cell_seq<<<512, 256, 0, stream>>>(scratch, G + (size_t)l * 512 * 4096,
                                      c_prev + (size_t)l * 512 * 1024, hidden, l);
  }
  gemm_heads<<<768, 256, 0, stream>>>(hidden, W_y, W_E, scratch);
  head_reduce<<<dim3(3, 512), 256, 0, stream>>>(scratch, b_y, b_E, (float*)d_out);
}

// Round 6
// 515.586 us; speedup vs baseline: 1.0157x; 1.0157x over previous
//
#include <hip/hip_runtime.h>

// ---------------------------------------------------------------------------
// Controller: 4-layer LSTM stack + two heads.  R6 = R5 design + fixes:
//  * FIX: gemm_gates l>0 epilogue was missing mbase in the G_il row index
//    (4 m-tiles raced on rows 0..127, rows 128..511 stayed poisoned).
//  * pack_w flattened: one 64x64 bf16 tile-slice per thread, grid 1376x256
//    (was 268 blocks / 1 wave/SIMD) for ~5x more memory-level parallelism.
//
// Design recap:
//  * pack_w: converts ALL weights fp32->bf16 into the exact per-tile LDS
//    image the GEMMs consume (XOR bank-swizzle pre-applied, Wg rows
//    gate-interleaved j=g*16+hh so a BN=64 tile holds all 4 gates for 16 h).
//  * GEMM staging = linear 32B/thread copy (no conversion, no index math).
//  * gates (K=1536, parallel over 4 layers): l==0 fuses the LSTM cell;
//    l>=1 writes G_il (bias folded).
//  * seq (K=1024 prev-layer slice, layers 1-3): fused cell epilogue.
//  * heads: split-K GEMM + reduce.
//
// ws layout (bytes):
//   A0    @ 0          bf16 [4][512][1536]                    6,291,456
//   PWg   @ 6291456    bf16 tile-img [4][64 nt][40 kt][8192B] 83,886,080
//   PWh   @ 90177536   bf16 tile-img [12 nt][64 kt][8192B]     6,291,456
//   G_il  @ 96468992   f32 [4][64 nt][512 b][64 j]            33,554,432
//   hidden@ 130023424  bf16 [512][4096]                        4,194,304
//   hpart @ 134217728  f32 [8][512][768]                      12,582,912
// ---------------------------------------------------------------------------

typedef short    shortx8  __attribute__((ext_vector_type(8)));
typedef float    floatx16 __attribute__((ext_vector_type(16)));

__device__ __forceinline__ unsigned int f2bf1(float x) {
  unsigned int u = __float_as_uint(x);
  return (u + 0x7fffu + ((u >> 16) & 1u)) >> 16;   // RNE to bf16 bits
}
__device__ __forceinline__ unsigned int f2bf2(float lo, float hi) {
  return f2bf1(lo) | (f2bf1(hi) << 16);
}
__device__ __forceinline__ float sigm(float x) { return 1.f / (1.f + __expf(-x)); }
__device__ __forceinline__ float tanh_(float x) { return 1.f - 2.f / (__expf(2.f * x) + 1.f); }

// ---------------------------------------------------------------------------
// prep_a0: A0[l][b][0:1536] = bf16(x[b] ++ h_prev[l][b]).  grid (384,4) x 256
// ---------------------------------------------------------------------------
__global__ __launch_bounds__(256) void prep_a0(const float* __restrict__ x,
                                               const float* __restrict__ hp,
                                               unsigned short* __restrict__ A0) {
  const int l   = blockIdx.y;
  const int idx = blockIdx.x * 256 + threadIdx.x;   // < 512*192
  const int b   = idx / 192;
  const int kk  = (idx - b * 192) * 8;
  float v[8];
  if (kk < 512) {
    const float* s = x + (size_t)b * 512 + kk;
#pragma unroll
    for (int i = 0; i < 8; ++i) v[i] = s[i];
  } else {
    const float* s = hp + ((size_t)l * 512 + b) * 1024 + (kk - 512);
#pragma unroll
    for (int i = 0; i < 8; ++i) v[i] = s[i];
  }
  uint4 o;
  o.x = f2bf2(v[0], v[1]); o.y = f2bf2(v[2], v[3]);
  o.z = f2bf2(v[4], v[5]); o.w = f2bf2(v[6], v[7]);
  *(uint4*)(A0 + ((size_t)l * 512 + b) * 1536 + kk) = o;
}

// ---------------------------------------------------------------------------
// pack_w: fp32 weights -> bf16 LDS-image tiles (64 rows x 64 k = 8192 B).
// image row j, group slot gd holds source k-group gd^(j&7) (bank swizzle).
// Wg tiles t<10240: l=t/2560, nt=(t%2560)/40, kt=t%40;
//   row(j) = l*4096 + (j>>4)*1024 + nt*16 + (j&15)  (gate-interleaved).
// Head tiles tp=t-10240<768: nt=tp>>6, kt=tp&63; row(j)=nt*64+j over [Wy;WE].
// grid 1376 x 256: thread (j,q) handles one quarter-row; block does 8 tiles.
// ---------------------------------------------------------------------------
__global__ __launch_bounds__(256) void pack_w(
    const float* __restrict__ Wg, const float* __restrict__ Wy,
    const float* __restrict__ WE, unsigned short* __restrict__ PWg,
    unsigned short* __restrict__ PWh) {
  const int tid = threadIdx.x;
  const int j = tid >> 2, q = tid & 3;
#pragma unroll
  for (int s = 0; s < 8; ++s) {
    const int t = blockIdx.x * 8 + s;
    const float* srow;
    unsigned short* dst;
    if (t < 10240) {
      const int l = t / 2560, rem = t - l * 2560;
      const int nt = rem / 40, kt = rem - nt * 40;
      const int wrow = l * 4096 + (j >> 4) * 1024 + nt * 16 + (j & 15);
      srow = Wg + (size_t)wrow * 2560 + kt * 64;
      dst  = PWg + (size_t)t * 4096;
    } else {
      const int tp = t - 10240;
      const int nt = tp >> 6, kt = tp & 63;
      const int r = nt * 64 + j;
      srow = (nt < 8) ? (Wy + (size_t)r * 4096 + kt * 64)
                      : (WE + (size_t)(r - 512) * 4096 + kt * 64);
      dst  = PWh + (size_t)tp * 4096;
    }
    const float4 v0 = ((const float4*)srow)[q * 4 + 0];
    const float4 v1 = ((const float4*)srow)[q * 4 + 1];
    const float4 v2 = ((const float4*)srow)[q * 4 + 2];
    const float4 v3 = ((const float4*)srow)[q * 4 + 3];
    uint4 o0, o1;
    o0.x = f2bf2(v0.x, v0.y); o0.y = f2bf2(v0.z, v0.w);
    o0.z = f2bf2(v1.x, v1.y); o0.w = f2bf2(v1.z, v1.w);
    o1.x = f2bf2(v2.x, v2.y); o1.y = f2bf2(v2.z, v2.w);
    o1.z = f2bf2(v3.x, v3.y); o1.w = f2bf2(v3.z, v3.w);
    uint4* drow = (uint4*)(dst + j * 64);
    drow[(2 * q) ^ (j & 7)]     = o0;
    drow[(2 * q + 1) ^ (j & 7)] = o1;
  }
}

// ---------------------------------------------------------------------------
// gemm_gates: acc[b, j] = sum_{k<1536} A0[l][b][k] * Wg_img ; BM=128 BN=64
// BK=64, 4 waves (2m x 2n), single-buffer LDS, linear B staging from PWg.
// l==0: fused LSTM cell -> hidden.  l>=1: G_il = acc + bias.
// grid 1024, XCD-swizzled (4 mt of one (l,nt) share an XCD).
// ---------------------------------------------------------------------------
__global__ __launch_bounds__(256, 4) void gemm_gates(
    const unsigned short* __restrict__ A0, const unsigned short* __restrict__ PWg,
    const float* __restrict__ bg, const float* __restrict__ c_prev,
    float* __restrict__ G_il, unsigned short* __restrict__ hidden) {
  __shared__ __align__(16) char smem[36864];
  unsigned short* As = (unsigned short*)smem;            // 16 KB
  unsigned short* Bs = (unsigned short*)(smem + 16384);  //  8 KB
  float* Gex = (float*)smem;                             // 128x68 f32 (alias)
  const int tid = threadIdx.x, lane = tid & 63, wave = tid >> 6;
  const int id  = blockIdx.x;
  const int xcd = id & 7, jj = id >> 3;
  const int mt  = jj & 3, rest = jj >> 2;
  const int c   = xcd * 32 + rest;          // 0..255
  const int l   = c >> 6, nt = c & 63;
  const int mbase = mt * 128;
  const unsigned short* Ab = A0 + ((size_t)l * 512 + mbase) * 1536;
  const unsigned short* Bt = PWg + ((size_t)(l * 64 + nt) * 40) * 4096;
  const int arow = tid >> 3, akg = tid & 7;

  floatx16 acc[2];
#pragma unroll
  for (int r = 0; r < 16; ++r) { acc[0][r] = 0.f; acc[1][r] = 0.f; }
  const int wm = (wave >> 1) * 64, wn = (wave & 1) * 32;

  for (int kt = 0; kt < 24; ++kt) {
    uint4 av[4];
#pragma unroll
    for (int r = 0; r < 4; ++r)
      av[r] = *(const uint4*)(Ab + (size_t)(arow + r * 32) * 1536 + kt * 64 + akg * 8);
    const uint4* bsrc = (const uint4*)(Bt + (size_t)kt * 4096);
    const uint4 b0 = bsrc[tid * 2];
    const uint4 b1 = bsrc[tid * 2 + 1];
    __syncthreads();
#pragma unroll
    for (int r = 0; r < 4; ++r) {
      const int row = arow + r * 32;
      *(uint4*)(&As[row * 64 + ((akg ^ (row & 7)) * 8)]) = av[r];
    }
    ((uint4*)Bs)[tid * 2] = b0;
    ((uint4*)Bs)[tid * 2 + 1] = b1;
    __syncthreads();
#pragma unroll
    for (int ks = 0; ks < 4; ++ks) {
      const int gb = ks * 2 + (lane >> 5);
      const int rowb = wn + (lane & 31);
      const shortx8 bfv = *(const shortx8*)(&Bs[rowb * 64 + ((gb ^ (rowb & 7)) * 8)]);
#pragma unroll
      for (int sm = 0; sm < 2; ++sm) {
        const int rowa = wm + sm * 32 + (lane & 31);
        const shortx8 af = *(const shortx8*)(&As[rowa * 64 + ((gb ^ (rowa & 7)) * 8)]);
        acc[sm] = __builtin_amdgcn_mfma_f32_32x32x16_bf16(af, bfv, acc[sm], 0, 0, 0);
      }
    }
  }

  const int col = wn + (lane & 31);                       // j in 0..63
  if (l > 0) {
    const int wrow = (col >> 4) * 1024 + nt * 16 + (col & 15);
    const float bias = bg[(size_t)l * 4096 + wrow];
    float* Go = G_il + ((size_t)(l * 64 + nt) * 512) * 64;
#pragma unroll
    for (int sm = 0; sm < 2; ++sm)
#pragma unroll
      for (int r = 0; r < 16; ++r) {
        const int row = mbase + wm + sm * 32 +            // FIX: mbase was missing
                        ((r & 3) + 8 * (r >> 2) + 4 * (lane >> 5));
        Go[(size_t)row * 64 + col] = acc[sm][r] + bias;
      }
  } else {
    __syncthreads();   // done reading As/Bs; reuse as Gex
#pragma unroll
    for (int sm = 0; sm < 2; ++sm)
#pragma unroll
      for (int r = 0; r < 16; ++r) {
        const int row = wm + sm * 32 + ((r & 3) + 8 * (r >> 2) + 4 * (lane >> 5));
        Gex[row * 68 + col] = acc[sm][r];
      }
    __syncthreads();
    const int hh = tid & 15, q = tid >> 4;   // q 0..15
    const int hg = nt * 16 + hh;
#pragma unroll
    for (int bi = 0; bi < 8; ++bi) {
      const int bl = bi * 16 + q;            // 0..127
      const int b  = mbase + bl;
      float gv[4];
#pragma unroll
      for (int g = 0; g < 4; ++g)
        gv[g] = Gex[bl * 68 + g * 16 + hh] + bg[g * 1024 + hg];
      const float c_old = c_prev[(size_t)b * 1024 + hg];
      const float cc = sigm(gv[1]) * c_old + sigm(gv[0]) * tanh_(gv[3]);
      const float hn = sigm(gv[2]) * tanh_(cc);
      hidden[(size_t)b * 4096 + hg] = (unsigned short)f2bf1(hn);
    }
  }
}

// ---------------------------------------------------------------------------
// gemm_seq_cell: layers 1..3.  acc = hidden[l-1] . Wg_img[k 1536:2560],
// BM=64 BN=64 BK=64 (16 rounds), fused cell: g = acc + G_il (bias inside).
// grid 512, XCD-swizzled (8 mt of one nt share an XCD).
// ---------------------------------------------------------------------------
__global__ __launch_bounds__(256, 4) void gemm_seq_cell(
    const unsigned short* __restrict__ hidden_ro, const unsigned short* __restrict__ PWg,
    const float* __restrict__ G_il, const float* __restrict__ c_prev,
    unsigned short* __restrict__ hidden_w, int l) {
  __shared__ __align__(16) char smem[18432];
  unsigned short* As = (unsigned short*)smem;           // 8 KB
  unsigned short* Bs = (unsigned short*)(smem + 8192);  // 8 KB
  float* Gex = (float*)smem;                            // 64x68 f32 (alias)
  const int tid = threadIdx.x, lane = tid & 63, wave = tid >> 6;
  const int id  = blockIdx.x;
  const int xcd = id & 7, u = id >> 3;     // u 0..63
  const int mt  = u & 7, q8 = u >> 3;      // q8 0..7
  const int nt  = xcd * 8 + q8;
  const int mbase = mt * 64;
  const unsigned short* Ab = hidden_ro + (size_t)(l - 1) * 1024;   // lda 4096
  const unsigned short* Bt = PWg + ((size_t)(l * 64 + nt) * 40 + 24) * 4096;
  const int arow = tid >> 3, akg = tid & 7;   // arow 0..31

  floatx16 acc;
#pragma unroll
  for (int r = 0; r < 16; ++r) acc[r] = 0.f;
  const int wm = (wave & 1) * 32, wn = (wave >> 1) * 32;

  for (int kt = 0; kt < 16; ++kt) {
    uint4 av[2];
#pragma unroll
    for (int r = 0; r < 2; ++r)
      av[r] = *(const uint4*)(Ab + (size_t)(mbase + arow + r * 32) * 4096 + kt * 64 + akg * 8);
    const uint4* bsrc = (const uint4*)(Bt + (size_t)kt * 4096);
    const uint4 b0 = bsrc[tid * 2];
    const uint4 b1 = bsrc[tid * 2 + 1];
    __syncthreads();
#pragma unroll
    for (int r = 0; r < 2; ++r) {
      const int row = arow + r * 32;
      *(uint4*)(&As[row * 64 + ((akg ^ (row & 7)) * 8)]) = av[r];
    }
    ((uint4*)Bs)[tid * 2] = b0;
    ((uint4*)Bs)[tid * 2 + 1] = b1;
    __syncthreads();
#pragma unroll
    for (int ks = 0; ks < 4; ++ks) {
      const int gb = ks * 2 + (lane >> 5);
      const int rowa = wm + (lane & 31);
      const int rowb = wn + (lane & 31);
      const shortx8 af  = *(const shortx8*)(&As[rowa * 64 + ((gb ^ (rowa & 7)) * 8)]);
      const shortx8 bfv = *(const shortx8*)(&Bs[rowb * 64 + ((gb ^ (rowb & 7)) * 8)]);
      acc = __builtin_amdgcn_mfma_f32_32x32x16_bf16(af, bfv, acc, 0, 0, 0);
    }
  }

  __syncthreads();
  const int col = wn + (lane & 31);
#pragma unroll
  for (int r = 0; r < 16; ++r) {
    const int row = wm + ((r & 3) + 8 * (r >> 2) + 4 * (lane >> 5));
    Gex[row * 68 + col] = acc[r];
  }
  __syncthreads();
  const int hh = tid & 15, qq = tid >> 4;   // qq 0..15
  const int hg = nt * 16 + hh;
  const float* Gb = G_il + ((size_t)(l * 64 + nt) * 512) * 64;
#pragma unroll
  for (int bi = 0; bi < 4; ++bi) {
    const int bl = bi * 16 + qq;            // 0..63
    const int b  = mbase + bl;
    float gv[4];
#pragma unroll
    for (int g = 0; g < 4; ++g)
      gv[g] = Gex[bl * 68 + g * 16 + hh] + Gb[(size_t)b * 64 + g * 16 + hh];
    const float c_old = c_prev[((size_t)l * 512 + b) * 1024 + hg];
    const float cc = sigm(gv[1]) * c_old + sigm(gv[0]) * tanh_(gv[3]);
    const float hn = sigm(gv[2]) * tanh_(cc);
    hidden_w[(size_t)b * 4096 + l * 1024 + hg] = (unsigned short)f2bf1(hn);
  }
}

// ---------------------------------------------------------------------------
// gemm_heads: hpart[ks][b][n] = sum_{k in split} hidden[b][k]*W_img[n][k]
// BM=128 BN=64, split-K=8 (8 rounds each), grid 384 XCD-swizzled.
// ---------------------------------------------------------------------------
__global__ __launch_bounds__(256, 4) void gemm_heads(
    const unsigned short* __restrict__ A, const unsigned short* __restrict__ PWh,
    float* __restrict__ hpart) {
  __shared__ __align__(16) char smem[24576];
  unsigned short* As = (unsigned short*)smem;            // 16 KB
  unsigned short* Bs = (unsigned short*)(smem + 16384);  //  8 KB
  const int tid = threadIdx.x, lane = tid & 63, wave = tid >> 6;
  const int id  = blockIdx.x;
  const int xcd = id & 7, u = id >> 3;     // u 0..47
  const int mt  = u & 3, q = u >> 2;       // q 0..11
  const int combo = xcd * 12 + q;          // 0..95
  const int nt  = combo % 12, ks0 = combo / 12;
  const int mbase = mt * 128;
  const unsigned short* Ab = A + (size_t)mbase * 4096;
  const unsigned short* Bt = PWh + ((size_t)nt * 64 + ks0 * 8) * 4096;
  const int arow = tid >> 3, akg = tid & 7;

  floatx16 acc[2];
#pragma unroll
  for (int r = 0; r < 16; ++r) { acc[0][r] = 0.f; acc[1][r] = 0.f; }
  const int wm = (wave >> 1) * 64, wn = (wave & 1) * 32;

  for (int kt = 0; kt < 8; ++kt) {
    uint4 av[4];
#pragma unroll
    for (int r = 0; r < 4; ++r)
      av[r] = *(const uint4*)(Ab + (size_t)(arow + r * 32) * 4096 +
                              ks0 * 512 + kt * 64 + akg * 8);
    const uint4* bsrc = (const uint4*)(Bt + (size_t)kt * 4096);
    const uint4 b0 = bsrc[tid * 2];
    const uint4 b1 = bsrc[tid * 2 + 1];
    __syncthreads();
#pragma unroll
    for (int r = 0; r < 4; ++r) {
      const int row = arow + r * 32;
      *(uint4*)(&As[row * 64 + ((akg ^ (row & 7)) * 8)]) = av[r];
    }
    ((uint4*)Bs)[tid * 2] = b0;
    ((uint4*)Bs)[tid * 2 + 1] = b1;
    __syncthreads();
#pragma unroll
    for (int ks = 0; ks < 4; ++ks) {
      const int gb = ks * 2 + (lane >> 5);
      const int rowb = wn + (lane & 31);
      const shortx8 bfv = *(const shortx8*)(&Bs[rowb * 64 + ((gb ^ (rowb & 7)) * 8)]);
#pragma unroll
      for (int sm = 0; sm < 2; ++sm) {
        const int rowa = wm + sm * 32 + (lane & 31);
        const shortx8 af = *(const shortx8*)(&As[rowa * 64 + ((gb ^ (rowa & 7)) * 8)]);
        acc[sm] = __builtin_amdgcn_mfma_f32_32x32x16_bf16(af, bfv, acc[sm], 0, 0, 0);
      }
    }
  }

  float* Co = hpart + (size_t)ks0 * 512 * 768;
  const int n = nt * 64 + wn + (lane & 31);
#pragma unroll
  for (int sm = 0; sm < 2; ++sm)
#pragma unroll
    for (int r = 0; r < 16; ++r) {
      const int row = mbase + wm + sm * 32 + ((r & 3) + 8 * (r >> 2) + 4 * (lane >> 5));
      Co[(size_t)row * 768 + n] = acc[sm][r];
    }
}

// ---------------------------------------------------------------------------
// head_reduce: sum 8 k-split partials + bias -> d_out.  grid (3,512) x 256
// ---------------------------------------------------------------------------
__global__ __launch_bounds__(256) void head_reduce(
    const float* __restrict__ hp, const float* __restrict__ b_y,
    const float* __restrict__ b_E, float* __restrict__ out) {
  const int n = blockIdx.x * 256 + threadIdx.x;  // 0..767
  const int b = blockIdx.y;
  float s = 0.f;
#pragma unroll
  for (int ks = 0; ks < 8; ++ks)
    s += hp[(size_t)ks * 512 * 768 + (size_t)b * 768 + n];
  if (n < 512)
    out[(size_t)b * 512 + n] = s + b_y[n];
  else
    out[(size_t)512 * 512 + (size_t)b * 256 + (n - 512)] = s + b_E[n - 512];
}

// ---------------------------------------------------------------------------
extern "C" void kernel_launch(void* const* d_in, const int* in_sizes, int n_in,
                              void* d_out, int out_size, void* d_ws, size_t ws_size,
                              hipStream_t stream) {
  const float* x      = (const float*)d_in[0];
  const float* h_prev = (const float*)d_in[1];
  const float* c_prev = (const float*)d_in[2];
  const float* Wg     = (const float*)d_in[3];
  const float* bg     = (const float*)d_in[4];
  const float* W_y    = (const float*)d_in[5];
  const float* b_y    = (const float*)d_in[6];
  const float* W_E    = (const float*)d_in[7];
  const float* b_E    = (const float*)d_in[8];

  char* ws = (char*)d_ws;
  unsigned short* A0     = (unsigned short*)(ws + 0);
  unsigned short* PWg    = (unsigned short*)(ws + 6291456);
  unsigned short* PWh    = (unsigned short*)(ws + 90177536);
  float*          G_il   = (float*)(ws + 96468992);
  unsigned short* hidden = (unsigned short*)(ws + 130023424);
  float*          hpart  = (float*)(ws + 134217728);

  prep_a0<<<dim3(384, 4), 256, 0, stream>>>(x, h_prev, A0);
  pack_w<<<1376, 256, 0, stream>>>(Wg, W_y, W_E, PWg, PWh);
  gemm_gates<<<1024, 256, 0, stream>>>(A0, PWg, bg, c_prev, G_il, hidden);
  for (int l = 1; l < 4; ++l)
    gemm_seq_cell<<<512, 256, 0, stream>>>(hidden, PWg, G_il, c_prev, hidden, l);
  gemm_heads<<<384, 256, 0, stream>>>(hidden, PWh, hpart);
  head_reduce<<<dim3(3, 512), 256, 0, stream>>>(hpart, b_y, b_E, (float*)d_out);
}